// Round 6
// baseline (216.810 us; speedup 1.0000x reference)
//
#include <hip/hip_runtime.h>

// Problem constants
#define BB   16
#define HEADS 8
#define DH   64
#define NSP  1024   // W*H = 32*32
#define CCH  512

typedef unsigned int   u32;
typedef unsigned short u16;
typedef __attribute__((ext_vector_type(8))) short  short8;   // 8 bf16 = 4 VGPR (MFMA A/B frag)
typedef __attribute__((ext_vector_type(4))) float  floatx4;  // 16x16 MFMA C/D frag
typedef __attribute__((ext_vector_type(16))) float floatx16; // 32x32 MFMA C/D frag
typedef __attribute__((ext_vector_type(2))) unsigned uint2v;

#if defined(__has_builtin)
#if __has_builtin(__builtin_amdgcn_exp2f)
#define EXP2F(x) __builtin_amdgcn_exp2f(x)
#else
#define EXP2F(x) exp2f(x)
#endif
#if __has_builtin(__builtin_amdgcn_permlane32_swap)
#define HAVE_PL32 1
#endif
#else
#define EXP2F(x) exp2f(x)
#endif

__device__ __forceinline__ u16 f2b(float f) {
  u32 x = __float_as_uint(f);
  x = x + 0x7fffu + ((x >> 16) & 1u);   // RNE
  return (u16)(x >> 16);
}

// pack two fp32 -> two bf16 (round-half-up ~= RNE) in one v_perm_b32
__device__ __forceinline__ u32 pkbf(float lo, float hi) {
  return __builtin_amdgcn_perm(__float_as_uint(hi) + 0x8000u,
                               __float_as_uint(lo) + 0x8000u, 0x07060302u);
}

__device__ __forceinline__ void gload_lds16(const u16* g, u16* l) {
  __builtin_amdgcn_global_load_lds((const __attribute__((address_space(1))) u32*)g,
                                   (__attribute__((address_space(3))) u32*)l, 16, 0, 0);
}

// lane32_swap(a,b): ap = {lanes<32: a, lanes>=32: b(l-32)}, bp = {lanes<32: a(l+32), lanes>=32: b}
__device__ __forceinline__ void lane32_swap(u32 a, u32 b, u32& ap, u32& bp, bool hi32) {
#ifdef HAVE_PL32
  uint2v r = __builtin_amdgcn_permlane32_swap(a, b, false, false);
  ap = r.x; bp = r.y;
  (void)hi32;
#else
  u32 sb = (u32)__shfl_xor((int)b, 32);
  u32 sa = (u32)__shfl_xor((int)a, 32);
  ap = hi32 ? sb : a;
  bp = hi32 ? b : sa;
#endif
}

// ---- fused prep: Wq/Wk/Wv cast (768 blk) | pos build (2048 blk) | x transpose (2048 blk)
__global__ __launch_bounds__(256) void prep_all(const float* __restrict__ x,
                                                const float* __restrict__ Wq,
                                                const float* __restrict__ Wk,
                                                const float* __restrict__ Wv,
                                                const float* __restrict__ rel_h,
                                                const float* __restrict__ rel_w,
                                                u16* __restrict__ wbf,
                                                u16* __restrict__ pos,
                                                u16* __restrict__ xt) {
  __shared__ float ld[64][68];
  int bid = blockIdx.x;
  int t = threadIdx.x;
  if (bid < 768) {
    // ---- W cast (o,c) fp32 -> bf16 ----
    int idx = bid * 256 + t;
    int which = idx >> 16;
    int r4 = (idx & 65535) * 4;
    const float* src = which == 0 ? Wq : which == 1 ? Wk : Wv;
    float4 v = *(const float4*)&src[r4];
    ushort4 s;
    s.x = f2b(v.x); s.y = f2b(v.y); s.z = f2b(v.z); s.w = f2b(v.w);
    *(ushort4*)&wbf[(which << 18) + r4] = s;
  } else if (bid < 2816) {
    // ---- pos[h][n][dd] = rel_h[h,dd,hh] + rel_w[h,dd,ww], n = ww*32+hh ----
    int idx = (bid - 768) * 256 + t;
    int dd = idx & 63;
    int n  = (idx >> 6) & 1023;
    int h  = idx >> 16;
    int ww = n >> 5, hh = n & 31;
    float v = rel_h[(h * 64 + dd) * 32 + hh] + rel_w[(h * 64 + dd) * 32 + ww];
    pos[idx] = f2b(v);
  } else {
    // ---- x [b][c][n] fp32 -> xt [b][n][c] bf16, 64x64 LDS tile ----
    int bid2 = bid - 2816;
    int ntile = bid2 & 15, ctile = (bid2 >> 4) & 7, b = bid2 >> 7;
    const float* xb = x + (((size_t)b * CCH + ctile * 64) << 10) + ntile * 64;
#pragma unroll
    for (int p = 0; p < 4; ++p) {
      int c = p * 16 + (t >> 4), n4 = (t & 15) * 4;
      float4 v = *(const float4*)&xb[((size_t)c << 10) + n4];
      ld[c][n4 + 0] = v.x; ld[c][n4 + 1] = v.y; ld[c][n4 + 2] = v.z; ld[c][n4 + 3] = v.w;
    }
    __syncthreads();
    u16* xo = xt + (((size_t)b << 10) + ntile * 64) * CCH + ctile * 64;
#pragma unroll
    for (int p = 0; p < 2; ++p) {
      int id = p * 256 + t;
      int n = id >> 3, c8 = (id & 7) * 8;
      ushort4 s0, s1;
      s0.x = f2b(ld[c8 + 0][n]); s0.y = f2b(ld[c8 + 1][n]);
      s0.z = f2b(ld[c8 + 2][n]); s0.w = f2b(ld[c8 + 3][n]);
      s1.x = f2b(ld[c8 + 4][n]); s1.y = f2b(ld[c8 + 5][n]);
      s1.z = f2b(ld[c8 + 6][n]); s1.w = f2b(ld[c8 + 7][n]);
      *(ushort4*)&xo[(size_t)n * CCH + c8] = s0;
      *(ushort4*)&xo[(size_t)n * CCH + c8 + 4] = s1;
    }
  }
}

// ---- FUSED QKV projection with T4 schedule + XCD-aware block remap. (unchanged)
__global__ __launch_bounds__(256, 2) void qkv_fused(const u16* __restrict__ wbf,
                                                    const u16* __restrict__ xt,
                                                    const float* __restrict__ bq,
                                                    const float* __restrict__ bk,
                                                    const float* __restrict__ bv,
                                                    u16* __restrict__ qw,
                                                    u16* __restrict__ kw,
                                                    u16* __restrict__ vtw) {
  int hid = blockIdx.x;             // 0..1023
  int xcd  = hid & 7;
  int slot = hid >> 3;              // 0..127
  int otile = slot & 7;
  int pair  = xcd * 16 + (slot >> 3);   // 0..127
  int ntile = pair & 7;
  int b     = pair >> 3;
  int o0 = otile * 64, n0 = ntile * 128;

  __shared__ __align__(16) u16 smem[2 * 20480];   // 80 KB: buf { Wq64 | Wk64 | Wv64 | X128 } x64c

  int t = threadIdx.x;
  int w = t >> 6, lane = t & 63;
  int l15 = lane & 15, quad = lane >> 4;
  int srow = lane >> 3, sc = lane & 7;
  int scc = (sc ^ srow) << 3;

  floatx4 aq[8], ak[8], av[8];
#pragma unroll
  for (int i = 0; i < 8; ++i) {
    aq[i] = (floatx4){0.f, 0.f, 0.f, 0.f};
    ak[i] = (floatx4){0.f, 0.f, 0.f, 0.f};
    av[i] = (floatx4){0.f, 0.f, 0.f, 0.f};
  }

  // staging: 320 rows of 64c: [0,64)Wq [64,128)Wk [128,192)Wv [192,320)X; 10 glds/wave
  auto stage = [&](int k0, int buf) {
    u16* base = smem + buf * 20480;
#pragma unroll
    for (int p = 0; p < 10; ++p) {
      int g0 = w * 80 + p * 8;     // uniform 8-row group base (tile bounds are x8)
      if (g0 < 192) {
        int which = g0 >> 6;
        int r0 = g0 & 63;
        gload_lds16(wbf + ((size_t)which << 18) + (size_t)(o0 + r0 + srow) * CCH + k0 + scc,
                    base + which * 4096 + r0 * 64);
      } else {
        int r0 = g0 - 192;
        gload_lds16(xt + (size_t)(b * 1024 + n0 + r0 + srow) * CCH + k0 + scc,
                    base + 12288 + r0 * 64);
      }
    }
  };

  int rs = l15 & 7;
  int c0 = (quad ^ rs) << 3;
  int c1 = ((4 + quad) ^ rs) << 3;
  int wrow = (w * 16 + l15) * 64;

  stage(0, 0);    // prologue DMA: 2-deep prefetch
  stage(64, 1);

  for (int ki = 0; ki < 8; ++ki) {
    // wait for THIS step's 10 DMAs only; step ki+1's 10 stay in flight
    if (ki < 7) asm volatile("s_waitcnt vmcnt(10)" ::: "memory");
    else        asm volatile("s_waitcnt vmcnt(0)" ::: "memory");
    __builtin_amdgcn_s_barrier();
    __builtin_amdgcn_sched_barrier(0);

    u16* base = smem + (ki & 1) * 20480;
    u16* Xb = base + 12288;
#pragma unroll
    for (int ks = 0; ks < 2; ++ks) {
      int cc = ks ? c1 : c0;
      short8 fq = *(short8*)&base[wrow + cc];
      short8 fk = *(short8*)&base[4096 + wrow + cc];
      short8 fv = *(short8*)&base[8192 + wrow + cc];
#pragma unroll
      for (int ns = 0; ns < 8; ++ns) {
        short8 fx = *(short8*)&Xb[(ns * 16 + l15) * 64 + cc];
        aq[ns] = __builtin_amdgcn_mfma_f32_16x16x32_bf16(fq, fx, aq[ns], 0, 0, 0);
        ak[ns] = __builtin_amdgcn_mfma_f32_16x16x32_bf16(fk, fx, ak[ns], 0, 0, 0);
        av[ns] = __builtin_amdgcn_mfma_f32_16x16x32_bf16(fx, fv, av[ns], 0, 0, 0);
      }
    }

    // post-compute join: buffer ki&1 dead for all waves before re-staging
    if (ki < 6) {
      __builtin_amdgcn_sched_barrier(0);
      __builtin_amdgcn_s_barrier();
      stage((ki + 2) * 64, ki & 1);
    }
  }

  // ---- epilogue: all three tiles through padded LDS -> coalesced dwordx4 stores ----
  __syncthreads();                 // staging buffers dead; reuse as transpose scratch
  u16* epQ = smem;                 // [128 n][72]  (144B rows, 16B-aligned)
  u16* epK = smem + 9216;
  u16* epV = smem + 18432;         // [64 o][136]  (272B rows)
  {
    int ob = o0 + w * 16 + quad * 4;
    float q0 = bq[ob], q1 = bq[ob + 1], q2 = bq[ob + 2], q3 = bq[ob + 3];
    float k0b = bk[ob], k1b = bk[ob + 1], k2b = bk[ob + 2], k3b = bk[ob + 3];
    float vb = bv[o0 + w * 16 + l15];
#pragma unroll
    for (int ns = 0; ns < 8; ++ns) {
      int n = ns * 16 + l15;
      uint2 pk;
      pk.x = pkbf(aq[ns][0] + q0, aq[ns][1] + q1);
      pk.y = pkbf(aq[ns][2] + q2, aq[ns][3] + q3);
      *(uint2*)&epQ[n * 72 + w * 16 + quad * 4] = pk;
      pk.x = pkbf(ak[ns][0] + k0b, ak[ns][1] + k1b);
      pk.y = pkbf(ak[ns][2] + k2b, ak[ns][3] + k3b);
      *(uint2*)&epK[n * 72 + w * 16 + quad * 4] = pk;
      pk.x = pkbf(av[ns][0] + vb, av[ns][1] + vb);
      pk.y = pkbf(av[ns][2] + vb, av[ns][3] + vb);
      *(uint2*)&epV[(w * 16 + l15) * 136 + ns * 16 + quad * 4] = pk;
    }
  }
  __syncthreads();
  int h = otile;
  {
    // Q/K: [bh][n][dd] rows, 128B each; thread = (row, half), 64B contiguous per thread
    int row = t >> 1, half = t & 1;
    size_t gb = ((size_t)(b * HEADS + h) * NSP + n0 + row) * 64 + half * 32;
#pragma unroll
    for (int i = 0; i < 4; ++i)
      *(uint4*)&qw[gb + i * 8] = *(uint4*)&epQ[row * 72 + half * 32 + i * 8];
#pragma unroll
    for (int i = 0; i < 4; ++i)
      *(uint4*)&kw[gb + i * 8] = *(uint4*)&epK[row * 72 + half * 32 + i * 8];
  }
  {
    // V: tiled [bh][nt][dd][nn]; thread = (dd=row, n-quarter), 64B contiguous per thread
    int row = t >> 2, q4 = t & 3;
#pragma unroll
    for (int i = 0; i < 4; ++i) {
      int nl = q4 * 32 + i * 8;
      int n = n0 + nl;
      int ntl = n >> 6, nn = n & 63;
      *(uint4*)&vtw[(((size_t)(b * HEADS + h) * 16 + ntl) * 64 + row) * 64 + nn]
          = *(uint4*)&epV[row * 136 + nl];
    }
  }
}

// ---- MFMA flash attention: 4 waves x 64m, triple-buffered staging, 1 barrier/tile,
// vmcnt(12) DMA pipeline — NOW on 32x32x16 MFMA (R6):
//   * 48 MFMA/tile/wave (was 96): -17% matrix-pipe cycles, half the issue slots
//   * C/D layout col=lane&31, row=(reg&3)+8*(reg>>2)+4*(lane>>5)  [HW-verified m74/m101]
//   * A/B frag: row|col=lane&31, k=(lane>>5)*8+j  -> same LDS tiles, chunk=(ks*2+(lane>>5))
//   * P->PV exchange collapses to 4 permlane32_swap per 32x32 subtile (no cndmask):
//     f0,f2 = swap(w0,w2); f1,f3 = swap(w1,w3)  (n-split across lane halves == k-split)
//   * lsum reduce: single shfl_xor(32)
__global__ __launch_bounds__(256, 2) void attn_mfma(const u16* __restrict__ qw,
                                                    const u16* __restrict__ kw,
                                                    const u16* __restrict__ vtw,
                                                    const u16* __restrict__ pos,
                                                    const float* __restrict__ x,
                                                    float* __restrict__ out) {
  int bh = blockIdx.x, mtile = blockIdx.y;
  int b = bh >> 3, h = bh & 7;
  __shared__ __align__(16) u16 smem_u16[36864];   // 72 KB: 3 bufs x {kt|qt|vt}
  // buf k: smem + k*12288 : kt [64n][64dd] | qt | vt [64dd][64n]  (chunk16 ^ row&7)

  int t = threadIdx.x;
  int w = t >> 6, lane = t & 63;
  int l31 = lane & 31, hi1 = lane >> 5;
  int hi8 = hi1 * 8;
  bool hi32 = hi1 != 0;
  size_t bhs = (size_t)bh;

  // loop-invariant B-operands: Q rows m, pos rows m (64 m per wave, 2 msub x 32)
  short8 qa[2][4], pa[2][4];
  {
    const short* qg = (const short*)qw + (bhs * NSP + mtile * 256 + w * 64) * 64;
    const short* pg = (const short*)pos + ((size_t)h * NSP + mtile * 256 + w * 64) * 64;
#pragma unroll
    for (int msub = 0; msub < 2; ++msub)
#pragma unroll
      for (int ks = 0; ks < 4; ++ks) {
        int off = (msub * 32 + l31) * 64 + ks * 16 + hi8;
        qa[msub][ks] = *(const short8*)(qg + off);
        pa[msub][ks] = *(const short8*)(pg + off);
      }
  }

  floatx16 oacc[2][2];   // [msub][ddsub]: dd = ddsub*32+(reg&3)+8*(reg>>2)+4*hi1, m = msub*32+l31
  float lsum[2] = {0.f, 0.f};
#pragma unroll
  for (int i = 0; i < 2; ++i)
#pragma unroll
    for (int j = 0; j < 2; ++j)
#pragma unroll
      for (int r = 0; r < 16; ++r) oacc[i][j][r] = 0.f;

  const u16* kg  = kw + bhs * NSP * 64;
  const u16* qgn = qw + bhs * NSP * 64;
  const u16* vg  = vtw + bhs * 16 * 4096;   // tiled [nt][64dd][64n]
  int srow = lane >> 3, sc = lane & 7;

  // stage tile nt into buffer buf: 6 DMAs per wave (2 row-groups x k/q/v)
  auto stage = [&](int nt, int buf) {
    u16* kt = smem_u16 + buf * 12288;
    u16* qt = kt + 4096;
    u16* vt = qt + 4096;
#pragma unroll
    for (int p = 0; p < 2; ++p) {
      int r0 = w * 16 + p * 8;
      int row = r0 + srow;
      int swz = ((sc ^ (row & 7)) << 3);
      gload_lds16(kg + (nt * 64 + row) * 64 + swz, &kt[r0 * 64]);
      gload_lds16(qgn + (nt * 64 + row) * 64 + swz, &qt[r0 * 64]);
      gload_lds16(vg + (size_t)nt * 4096 + row * 64 + swz, &vt[r0 * 64]);
    }
  };

  stage(0, 0);   // prologue DMA: 2-deep prefetch
  stage(1, 1);

  for (int nt = 0; nt < 16; ++nt) {
    __builtin_amdgcn_s_barrier();   // all waves finished compute of tile nt-1
    if (nt < 14) {
      stage(nt + 2, (nt + 2) % 3);  // its buffer is the one freed at nt-1
      // 18 outstanding after issue; <=12 left  <=>  tile nt's 6 have landed
      asm volatile("s_waitcnt vmcnt(12)" ::: "memory");
    } else if (nt == 14) {
      asm volatile("s_waitcnt vmcnt(6)" ::: "memory");
    } else {
      asm volatile("s_waitcnt vmcnt(0)" ::: "memory");
    }
    __builtin_amdgcn_sched_barrier(0);

    u16* kt = smem_u16 + (nt % 3) * 12288;
    u16* qt = kt + 4096;
    u16* vt = qt + 4096;

#pragma unroll
    for (int nsub = 0; nsub < 2; ++nsub) {
      // ---- A-fragments for S^T: K rows n (cc) + Q rows n (cp), 32 n ----
      short8 kf[4], qf[4];
      int rowA = nsub * 32 + l31, rx7 = rowA & 7;
#pragma unroll
      for (int ks = 0; ks < 4; ++ks) {
        int ad = rowA * 64 + (((ks * 2 + hi1) ^ rx7) << 3);
        kf[ks] = *(short8*)&kt[ad];
        qf[ks] = *(short8*)&qt[ad];
      }
      short8 pv0[2], pv1[2];   // PV B-frags: [msub], k-chunks nsub*2+0 / +1
#pragma unroll
      for (int msub = 0; msub < 2; ++msub) {
        floatx16 c;
#pragma unroll
        for (int r = 0; r < 16; ++r) c[r] = 0.f;
#pragma unroll
        for (int ks = 0; ks < 4; ++ks)
          c = __builtin_amdgcn_mfma_f32_32x32x16_bf16(kf[ks], qa[msub][ks], c, 0, 0, 0);
#pragma unroll
        for (int ks = 0; ks < 4; ++ks)
          c = __builtin_amdgcn_mfma_f32_32x32x16_bf16(qf[ks], pa[msub][ks], c, 0, 0, 0);
        // ---- softmax numerator: p = exp2(s*log2e - 8*log2e) ----
        float p[16];
#pragma unroll
        for (int r = 0; r < 16; ++r)
          p[r] = EXP2F(fmaf(c[r], 1.44269504f, -11.5415603f));
        lsum[msub] += (((p[0] + p[1]) + (p[2] + p[3])) + ((p[4] + p[5]) + (p[6] + p[7])))
                    + (((p[8] + p[9]) + (p[10] + p[11])) + ((p[12] + p[13]) + (p[14] + p[15])));
        u32 wp[8];
#pragma unroll
        for (int i = 0; i < 8; ++i) wp[i] = pkbf(p[2 * i], p[2 * i + 1]);
        // ---- in-register exchange -> PV B-fragments (4 permlane32_swap) ----
        u32 x0, y0, x1, y1, x2, y2, x3, y3;
        lane32_swap(wp[0], wp[2], x0, y0, hi32);
        lane32_swap(wp[1], wp[3], x1, y1, hi32);
        lane32_swap(wp[4], wp[6], x2, y2, hi32);
        lane32_swap(wp[5], wp[7], x3, y3, hi32);
        union { u32 u[4]; short8 s; } cv0, cv1;
        cv0.u[0] = x0; cv0.u[1] = x1; cv0.u[2] = y0; cv0.u[3] = y1;
        cv1.u[0] = x2; cv1.u[1] = x3; cv1.u[2] = y2; cv1.u[3] = y3;
        pv0[msub] = cv0.s;
        pv1[msub] = cv1.s;
      }
      // ---- PV for this nsub's 32 n: O^T += V^T · P^T (two K=16 chunks) ----
#pragma unroll
      for (int ddsub = 0; ddsub < 2; ++ddsub) {
        int rowV = ddsub * 32 + l31, rv7 = rowV & 7;
        int ksb = nsub * 2;
        short8 v0 = *(short8*)&vt[rowV * 64 + ((((ksb + 0) * 2 + hi1) ^ rv7) << 3)];
        short8 v1 = *(short8*)&vt[rowV * 64 + ((((ksb + 1) * 2 + hi1) ^ rv7) << 3)];
#pragma unroll
        for (int msub = 0; msub < 2; ++msub) {
          oacc[msub][ddsub] = __builtin_amdgcn_mfma_f32_32x32x16_bf16(v0, pv0[msub], oacc[msub][ddsub], 0, 0, 0);
          oacc[msub][ddsub] = __builtin_amdgcn_mfma_f32_32x32x16_bf16(v1, pv1[msub], oacc[msub][ddsub], 0, 0, 0);
        }
      }
    }
  }

  // ---- row-sum reduction (column m is held by the 2 lane-halves) ----
  float rinv[2];
#pragma unroll
  for (int msub = 0; msub < 2; ++msub) {
    float l = lsum[msub];
    l += __shfl_xor(l, 32);
    rinv[msub] = 1.0f / l;
  }

  // ---- epilogue: wave-private LDS transpose, two 32-m halves, float4 stores ----
  __syncthreads();   // all waves done with buffers before smem reuse
  float* ot = (float*)smem_u16 + w * 2304;   // 64dd x 36  (36 KB total, fits)
  int l8 = lane & 7, lr = lane >> 3;
#pragma unroll
  for (int mh = 0; mh < 2; ++mh) {           // mh == msub (32 m each)
#pragma unroll
    for (int ddsub = 0; ddsub < 2; ++ddsub)
#pragma unroll
      for (int r = 0; r < 16; ++r) {
        int dd = ddsub * 32 + (r & 3) + 8 * (r >> 2) + 4 * hi1;
        ot[dd * 36 + l31] = oacc[mh][ddsub][r] * rinv[mh];
      }
    // intra-wave LDS ops are in-order; no barrier needed
#pragma unroll
    for (int pass = 0; pass < 8; ++pass) {
      int dd = pass * 8 + lr;
      float4 o4 = *(float4*)&ot[dd * 36 + l8 * 4];
      size_t off = (((size_t)b * CCH + h * DH + dd) << 10) + mtile * 256 + w * 64 + mh * 32 + l8 * 4;
      float4 xv = *(const float4*)&x[off];
      o4.x += xv.x; o4.y += xv.y; o4.z += xv.z; o4.w += xv.w;
      *(float4*)&out[off] = o4;
    }
  }
}

extern "C" void kernel_launch(void* const* d_in, const int* in_sizes, int n_in,
                              void* d_out, int out_size, void* d_ws, size_t ws_size,
                              hipStream_t stream) {
  const float* x     = (const float*)d_in[0];
  const float* Wq    = (const float*)d_in[1];
  const float* bq    = (const float*)d_in[2];
  const float* Wk    = (const float*)d_in[3];
  const float* bk    = (const float*)d_in[4];
  const float* Wv    = (const float*)d_in[5];
  const float* bv    = (const float*)d_in[6];
  const float* rel_h = (const float*)d_in[7];
  const float* rel_w = (const float*)d_in[8];
  // d_in[9] (reg_qk) and d_in[10] (reg_v) provably do not affect the output.
  float* out = (float*)d_out;

  char* ws = (char*)d_ws;
  u16* qw   = (u16*)(ws);                          // 16 MB  [b,h,n,dd]
  u16* kw   = (u16*)(ws + ((size_t)16 << 20));     // 16 MB  [b,h,n,dd]
  u16* vtw  = (u16*)(ws + ((size_t)32 << 20));     // 16 MB  [bh][nt16][dd64][nn64]
  u16* pos  = (u16*)(ws + ((size_t)48 << 20));     // 1 MB   [h,n,dd]
  u16* wbf  = (u16*)(ws + ((size_t)49 << 20));     // 1.5 MB [which][o][c] bf16
  u16* xt   = (u16*)d_out;                         // xT bf16 parked in d_out (overwritten later)

  hipLaunchKernelGGL(prep_all, dim3(4864), dim3(256), 0, stream,
                     x, Wq, Wk, Wv, rel_h, rel_w, wbf, pos, xt);
  hipLaunchKernelGGL(qkv_fused, dim3(1024), dim3(256), 0, stream,
                     wbf, xt, bq, bk, bv, qw, kw, vtw);
  hipLaunchKernelGGL(attn_mfma, dim3(128, 4), dim3(256), 0, stream,
                     qw, kw, vtw, pos, x, out);
}

// Round 7
// 209.835 us; speedup vs baseline: 1.0332x; 1.0332x over previous
//
#include <hip/hip_runtime.h>

// Problem constants
#define BB   16
#define HEADS 8
#define DH   64
#define NSP  1024   // W*H = 32*32
#define CCH  512

typedef unsigned int   u32;
typedef unsigned short u16;
typedef __attribute__((ext_vector_type(8))) short  short8;   // 8 bf16 = 4 VGPR (MFMA A/B frag)
typedef __attribute__((ext_vector_type(4))) float  floatx4;  // MFMA C/D frag
typedef __attribute__((ext_vector_type(2))) unsigned uint2v;

#if defined(__has_builtin)
#if __has_builtin(__builtin_amdgcn_exp2f)
#define EXP2F(x) __builtin_amdgcn_exp2f(x)
#else
#define EXP2F(x) exp2f(x)
#endif
#if __has_builtin(__builtin_amdgcn_permlane32_swap)
#define HAVE_PL32 1
#endif
#if __has_builtin(__builtin_amdgcn_permlane16_swap)
#define HAVE_PL16 1
#endif
#else
#define EXP2F(x) exp2f(x)
#endif

__device__ __forceinline__ u16 f2b(float f) {
  u32 x = __float_as_uint(f);
  x = x + 0x7fffu + ((x >> 16) & 1u);   // RNE
  return (u16)(x >> 16);
}

// pack two fp32 -> two bf16 (round-half-up ~= RNE) in one v_perm_b32
__device__ __forceinline__ u32 pkbf(float lo, float hi) {
  return __builtin_amdgcn_perm(__float_as_uint(hi) + 0x8000u,
                               __float_as_uint(lo) + 0x8000u, 0x07060302u);
}

__device__ __forceinline__ void gload_lds16(const u16* g, u16* l) {
  __builtin_amdgcn_global_load_lds((const __attribute__((address_space(1))) u32*)g,
                                   (__attribute__((address_space(3))) u32*)l, 16, 0, 0);
}

// ---- cross-lane helpers for the in-register P quad-exchange ----
// lane32_swap(a,b): ap = {a.lo32lanes, b.lo32lanes}, bp = {a.hi, b.hi}
__device__ __forceinline__ void lane32_swap(u32 a, u32 b, u32& ap, u32& bp, bool hi32) {
#ifdef HAVE_PL32
  uint2v r = __builtin_amdgcn_permlane32_swap(a, b, false, false);
  ap = r.x; bp = r.y;
  (void)hi32;
#else
  u32 sb = (u32)__shfl_xor((int)b, 32);
  u32 sa = (u32)__shfl_xor((int)a, 32);
  ap = hi32 ? sb : a;
  bp = hi32 ? b : sa;
#endif
}

// returns x from lane^16 (quad-pair exchange 0<->1, 2<->3)
__device__ __forceinline__ u32 lane16_xor(u32 x, bool qodd) {
#ifdef HAVE_PL16
  uint2v r = __builtin_amdgcn_permlane16_swap(x, x, false, false);
  // r.x = {q0,q0,q2,q2}, r.y = {q1,q1,q3,q3} -> xor16 = qodd ? r.x : r.y
  return qodd ? r.x : r.y;
#else
  return (u32)__shfl_xor((int)x, 16);
#endif
}

// ---- fused prep: Wq/Wk/Wv cast (768 blk) | pos build (2048 blk) | x transpose (2048 blk)
__global__ __launch_bounds__(256) void prep_all(const float* __restrict__ x,
                                                const float* __restrict__ Wq,
                                                const float* __restrict__ Wk,
                                                const float* __restrict__ Wv,
                                                const float* __restrict__ rel_h,
                                                const float* __restrict__ rel_w,
                                                u16* __restrict__ wbf,
                                                u16* __restrict__ pos,
                                                u16* __restrict__ xt) {
  __shared__ float ld[64][68];
  int bid = blockIdx.x;
  int t = threadIdx.x;
  if (bid < 768) {
    // ---- W cast (o,c) fp32 -> bf16 ----
    int idx = bid * 256 + t;
    int which = idx >> 16;
    int r4 = (idx & 65535) * 4;
    const float* src = which == 0 ? Wq : which == 1 ? Wk : Wv;
    float4 v = *(const float4*)&src[r4];
    ushort4 s;
    s.x = f2b(v.x); s.y = f2b(v.y); s.z = f2b(v.z); s.w = f2b(v.w);
    *(ushort4*)&wbf[(which << 18) + r4] = s;
  } else if (bid < 2816) {
    // ---- pos[h][n][dd] = rel_h[h,dd,hh] + rel_w[h,dd,ww], n = ww*32+hh ----
    int idx = (bid - 768) * 256 + t;
    int dd = idx & 63;
    int n  = (idx >> 6) & 1023;
    int h  = idx >> 16;
    int ww = n >> 5, hh = n & 31;
    float v = rel_h[(h * 64 + dd) * 32 + hh] + rel_w[(h * 64 + dd) * 32 + ww];
    pos[idx] = f2b(v);
  } else {
    // ---- x [b][c][n] fp32 -> xt [b][n][c] bf16, 64x64 LDS tile ----
    int bid2 = bid - 2816;
    int ntile = bid2 & 15, ctile = (bid2 >> 4) & 7, b = bid2 >> 7;
    const float* xb = x + (((size_t)b * CCH + ctile * 64) << 10) + ntile * 64;
#pragma unroll
    for (int p = 0; p < 4; ++p) {
      int c = p * 16 + (t >> 4), n4 = (t & 15) * 4;
      float4 v = *(const float4*)&xb[((size_t)c << 10) + n4];
      ld[c][n4 + 0] = v.x; ld[c][n4 + 1] = v.y; ld[c][n4 + 2] = v.z; ld[c][n4 + 3] = v.w;
    }
    __syncthreads();
    u16* xo = xt + (((size_t)b << 10) + ntile * 64) * CCH + ctile * 64;
#pragma unroll
    for (int p = 0; p < 2; ++p) {
      int id = p * 256 + t;
      int n = id >> 3, c8 = (id & 7) * 8;
      ushort4 s0, s1;
      s0.x = f2b(ld[c8 + 0][n]); s0.y = f2b(ld[c8 + 1][n]);
      s0.z = f2b(ld[c8 + 2][n]); s0.w = f2b(ld[c8 + 3][n]);
      s1.x = f2b(ld[c8 + 4][n]); s1.y = f2b(ld[c8 + 5][n]);
      s1.z = f2b(ld[c8 + 6][n]); s1.w = f2b(ld[c8 + 7][n]);
      *(ushort4*)&xo[(size_t)n * CCH + c8] = s0;
      *(ushort4*)&xo[(size_t)n * CCH + c8 + 4] = s1;
    }
  }
}

// ---- FUSED QKV projection with T4 schedule + XCD-aware block remap. (unchanged)
__global__ __launch_bounds__(256, 2) void qkv_fused(const u16* __restrict__ wbf,
                                                    const u16* __restrict__ xt,
                                                    const float* __restrict__ bq,
                                                    const float* __restrict__ bk,
                                                    const float* __restrict__ bv,
                                                    u16* __restrict__ qw,
                                                    u16* __restrict__ kw,
                                                    u16* __restrict__ vtw) {
  int hid = blockIdx.x;             // 0..1023
  int xcd  = hid & 7;
  int slot = hid >> 3;              // 0..127
  int otile = slot & 7;
  int pair  = xcd * 16 + (slot >> 3);   // 0..127
  int ntile = pair & 7;
  int b     = pair >> 3;
  int o0 = otile * 64, n0 = ntile * 128;

  __shared__ __align__(16) u16 smem[2 * 20480];   // 80 KB: buf { Wq64 | Wk64 | Wv64 | X128 } x64c

  int t = threadIdx.x;
  int w = t >> 6, lane = t & 63;
  int l15 = lane & 15, quad = lane >> 4;
  int srow = lane >> 3, sc = lane & 7;
  int scc = (sc ^ srow) << 3;

  floatx4 aq[8], ak[8], av[8];
#pragma unroll
  for (int i = 0; i < 8; ++i) {
    aq[i] = (floatx4){0.f, 0.f, 0.f, 0.f};
    ak[i] = (floatx4){0.f, 0.f, 0.f, 0.f};
    av[i] = (floatx4){0.f, 0.f, 0.f, 0.f};
  }

  // staging: 320 rows of 64c: [0,64)Wq [64,128)Wk [128,192)Wv [192,320)X; 10 glds/wave
  auto stage = [&](int k0, int buf) {
    u16* base = smem + buf * 20480;
#pragma unroll
    for (int p = 0; p < 10; ++p) {
      int g0 = w * 80 + p * 8;     // uniform 8-row group base (tile bounds are x8)
      if (g0 < 192) {
        int which = g0 >> 6;
        int r0 = g0 & 63;
        gload_lds16(wbf + ((size_t)which << 18) + (size_t)(o0 + r0 + srow) * CCH + k0 + scc,
                    base + which * 4096 + r0 * 64);
      } else {
        int r0 = g0 - 192;
        gload_lds16(xt + (size_t)(b * 1024 + n0 + r0 + srow) * CCH + k0 + scc,
                    base + 12288 + r0 * 64);
      }
    }
  };

  int rs = l15 & 7;
  int c0 = (quad ^ rs) << 3;
  int c1 = ((4 + quad) ^ rs) << 3;
  int wrow = (w * 16 + l15) * 64;

  stage(0, 0);    // prologue DMA: 2-deep prefetch
  stage(64, 1);

  for (int ki = 0; ki < 8; ++ki) {
    // wait for THIS step's 10 DMAs only; step ki+1's 10 stay in flight
    if (ki < 7) asm volatile("s_waitcnt vmcnt(10)" ::: "memory");
    else        asm volatile("s_waitcnt vmcnt(0)" ::: "memory");
    __builtin_amdgcn_s_barrier();
    __builtin_amdgcn_sched_barrier(0);

    u16* base = smem + (ki & 1) * 20480;
    u16* Xb = base + 12288;
#pragma unroll
    for (int ks = 0; ks < 2; ++ks) {
      int cc = ks ? c1 : c0;
      short8 fq = *(short8*)&base[wrow + cc];
      short8 fk = *(short8*)&base[4096 + wrow + cc];
      short8 fv = *(short8*)&base[8192 + wrow + cc];
#pragma unroll
      for (int ns = 0; ns < 8; ++ns) {
        short8 fx = *(short8*)&Xb[(ns * 16 + l15) * 64 + cc];
        aq[ns] = __builtin_amdgcn_mfma_f32_16x16x32_bf16(fq, fx, aq[ns], 0, 0, 0);
        ak[ns] = __builtin_amdgcn_mfma_f32_16x16x32_bf16(fk, fx, ak[ns], 0, 0, 0);
        av[ns] = __builtin_amdgcn_mfma_f32_16x16x32_bf16(fx, fv, av[ns], 0, 0, 0);
      }
    }

    // post-compute join: buffer ki&1 dead for all waves before re-staging
    if (ki < 6) {
      __builtin_amdgcn_sched_barrier(0);
      __builtin_amdgcn_s_barrier();
      stage((ki + 2) * 64, ki & 1);
    }
  }

  // ---- epilogue: all three tiles through padded LDS -> coalesced dwordx4 stores ----
  __syncthreads();                 // staging buffers dead; reuse as transpose scratch
  u16* epQ = smem;                 // [128 n][72]  (144B rows, 16B-aligned)
  u16* epK = smem + 9216;
  u16* epV = smem + 18432;         // [64 o][136]  (272B rows)
  {
    int ob = o0 + w * 16 + quad * 4;
    float q0 = bq[ob], q1 = bq[ob + 1], q2 = bq[ob + 2], q3 = bq[ob + 3];
    float k0b = bk[ob], k1b = bk[ob + 1], k2b = bk[ob + 2], k3b = bk[ob + 3];
    float vb = bv[o0 + w * 16 + l15];
#pragma unroll
    for (int ns = 0; ns < 8; ++ns) {
      int n = ns * 16 + l15;
      uint2 pk;
      pk.x = pkbf(aq[ns][0] + q0, aq[ns][1] + q1);
      pk.y = pkbf(aq[ns][2] + q2, aq[ns][3] + q3);
      *(uint2*)&epQ[n * 72 + w * 16 + quad * 4] = pk;
      pk.x = pkbf(ak[ns][0] + k0b, ak[ns][1] + k1b);
      pk.y = pkbf(ak[ns][2] + k2b, ak[ns][3] + k3b);
      *(uint2*)&epK[n * 72 + w * 16 + quad * 4] = pk;
      pk.x = pkbf(av[ns][0] + vb, av[ns][1] + vb);
      pk.y = pkbf(av[ns][2] + vb, av[ns][3] + vb);
      *(uint2*)&epV[(w * 16 + l15) * 136 + ns * 16 + quad * 4] = pk;
    }
  }
  __syncthreads();
  int h = otile;
  {
    // Q/K: [bh][n][dd] rows, 128B each; thread = (row, half), 64B contiguous per thread
    int row = t >> 1, half = t & 1;
    size_t gb = ((size_t)(b * HEADS + h) * NSP + n0 + row) * 64 + half * 32;
#pragma unroll
    for (int i = 0; i < 4; ++i)
      *(uint4*)&qw[gb + i * 8] = *(uint4*)&epQ[row * 72 + half * 32 + i * 8];
#pragma unroll
    for (int i = 0; i < 4; ++i)
      *(uint4*)&kw[gb + i * 8] = *(uint4*)&epK[row * 72 + half * 32 + i * 8];
  }
  {
    // V: tiled [bh][nt][dd][nn]; thread = (dd=row, n-quarter), 64B contiguous per thread
    int row = t >> 2, q4 = t & 3;
#pragma unroll
    for (int i = 0; i < 4; ++i) {
      int nl = q4 * 32 + i * 8;
      int n = n0 + nl;
      int ntl = n >> 6, nn = n & 63;
      *(uint4*)&vtw[(((size_t)(b * HEADS + h) * 16 + ntl) * 64 + row) * 64 + nn]
          = *(uint4*)&epV[row * 136 + nl];
    }
  }
}

// ---- MFMA flash attention: 8 waves x 32 m (R7).
// R6 post-mortem: 32x32 MFMA reverted (inherent 4-way LDS conflict, same pipe
// cycles). Corrected cycle model: at 2 waves/SIMD the lockstep tile period is
// 3.5x the MFMA-pipe floor -> dependency-stall-bound. This round re-tests TLP
// (R1's 8-wave) on the CURRENT structure, with R1's three regression causes
// eliminated: no pt LDS roundtrip (in-reg exchange), counted-vmcnt triple
// buffer (1 barrier/tile), and full-128B-line epilogue stores.
// 512 thr, LDS 72 KB -> 2 blocks/CU -> 4 waves/SIMD (2x TLP), ~110 VGPR.
__global__ __launch_bounds__(512, 4) void attn_mfma(const u16* __restrict__ qw,
                                                    const u16* __restrict__ kw,
                                                    const u16* __restrict__ vtw,
                                                    const u16* __restrict__ pos,
                                                    const float* __restrict__ x,
                                                    float* __restrict__ out) {
  int bh = blockIdx.x, mtile = blockIdx.y;
  int b = bh >> 3, h = bh & 7;
  __shared__ __align__(16) u16 smem_u16[36864];   // 72 KB: 3 bufs x {kt|qt|vt}
  // buf k: smem + k*12288 : kt [64n][64dd] | qt | vt [64dd][64n]  (chunk16 ^ row&7)

  int t = threadIdx.x;
  int w = t >> 6, lane = t & 63;        // 8 waves, wave w owns m rows w*32..w*32+31
  int l15 = lane & 15, quad = lane >> 4;
  bool qodd = (quad & 1) != 0;
  bool hi32 = lane >= 32;
  size_t bhs = (size_t)bh;

  // loop-invariant fragments: q_m, pos_m (MFMA B-operands), 32 rows per wave
  short8 qa[2][2], pa[2][2];
  {
    const short* qg = (const short*)qw + (bhs * NSP + mtile * 256 + w * 32) * 64;
    const short* pg = (const short*)pos + ((size_t)h * NSP + mtile * 256 + w * 32) * 64;
#pragma unroll
    for (int msub = 0; msub < 2; ++msub)
#pragma unroll
      for (int ks = 0; ks < 2; ++ks) {
        int off = (msub * 16 + l15) * 64 + ks * 32 + quad * 8;
        qa[msub][ks] = *(const short8*)(qg + off);
        pa[msub][ks] = *(const short8*)(pg + off);
      }
  }

  floatx4 oacc[2][4];   // [msub][ddsub]: dd = ddsub*16+quad*4+r, m = msub*16+l15 (+w*32)
  float lsum[2] = {0.f, 0.f};
#pragma unroll
  for (int i = 0; i < 2; ++i)
#pragma unroll
    for (int j = 0; j < 4; ++j) oacc[i][j] = (floatx4){0.f, 0.f, 0.f, 0.f};

  const u16* kg  = kw + bhs * NSP * 64;
  const u16* qgn = qw + bhs * NSP * 64;
  const u16* vg  = vtw + bhs * 16 * 4096;   // tiled [nt][64dd][64n]
  int srow = lane >> 3, sc = lane & 7;

  // hoisted swizzle invariants
  int rs = l15 & 7;
  int c0 = (quad ^ rs) << 3;        // S-phase B-frag chunk offsets (u16 units)
  int c1 = ((4 + quad) ^ rs) << 3;

  // stage tile nt into buffer buf: 3 DMAs per wave (1 row-group x k/q/v)
  auto stage = [&](int nt, int buf) {
    u16* kt = smem_u16 + buf * 12288;
    u16* qt = kt + 4096;
    u16* vt = qt + 4096;
    int r0 = w * 8;
    int row = r0 + srow;
    int swz = ((sc ^ (row & 7)) << 3);
    gload_lds16(kg + (nt * 64 + row) * 64 + swz, &kt[r0 * 64]);
    gload_lds16(qgn + (nt * 64 + row) * 64 + swz, &qt[r0 * 64]);
    gload_lds16(vg + (size_t)nt * 4096 + row * 64 + swz, &vt[r0 * 64]);
  };

  stage(0, 0);   // prologue DMA: 2-deep prefetch
  stage(1, 1);

  for (int nt = 0; nt < 16; ++nt) {
    __builtin_amdgcn_s_barrier();   // all waves finished compute of tile nt-1
    if (nt < 14) {
      stage(nt + 2, (nt + 2) % 3);  // its buffer is the one freed at nt-1
      // <=9 outstanding after issue; <=6 left  <=>  tile nt's 3 have landed
      asm volatile("s_waitcnt vmcnt(6)" ::: "memory");
    } else if (nt == 14) {
      asm volatile("s_waitcnt vmcnt(3)" ::: "memory");
    } else {
      asm volatile("s_waitcnt vmcnt(0)" ::: "memory");
    }
    __builtin_amdgcn_sched_barrier(0);

    u16* kt = smem_u16 + (nt % 3) * 12288;
    u16* qt = kt + 4096;
    u16* vt = qt + 4096;

#pragma unroll
    for (int half = 0; half < 2; ++half) {
      // ---- S^T + softmax numerator for 32 n (2 nblk); P stays in registers ----
      u32 Wd[2][4];   // [msub][word]: word nblk2*2+rp packs n_local = nblk2*16+quad*4+2rp,+1
#pragma unroll
      for (int nblk2 = 0; nblk2 < 2; ++nblk2) {
        int nblk = half * 2 + nblk2;
        int rb = (nblk * 16 + l15) * 64;
        short8 kb0 = *(short8*)&kt[rb + c0];
        short8 kb1 = *(short8*)&kt[rb + c1];
        short8 qb0 = *(short8*)&qt[rb + c0];
        short8 qb1 = *(short8*)&qt[rb + c1];
        floatx4 sc4[2];
#pragma unroll
        for (int msub = 0; msub < 2; ++msub) {
          floatx4 c = (floatx4){0.f, 0.f, 0.f, 0.f};
          c = __builtin_amdgcn_mfma_f32_16x16x32_bf16(kb0, qa[msub][0], c, 0, 0, 0);
          c = __builtin_amdgcn_mfma_f32_16x16x32_bf16(kb1, qa[msub][1], c, 0, 0, 0);
          c = __builtin_amdgcn_mfma_f32_16x16x32_bf16(qb0, pa[msub][0], c, 0, 0, 0);
          c = __builtin_amdgcn_mfma_f32_16x16x32_bf16(qb1, pa[msub][1], c, 0, 0, 0);
          sc4[msub] = c;
        }
#pragma unroll
        for (int msub = 0; msub < 2; ++msub) {
          // p = exp(s - 8) = exp2(s*log2e - 8*log2e)
          float p0 = EXP2F(fmaf(sc4[msub][0], 1.44269504f, -11.5415603f));
          float p1 = EXP2F(fmaf(sc4[msub][1], 1.44269504f, -11.5415603f));
          float p2 = EXP2F(fmaf(sc4[msub][2], 1.44269504f, -11.5415603f));
          float p3 = EXP2F(fmaf(sc4[msub][3], 1.44269504f, -11.5415603f));
          lsum[msub] += (p0 + p1) + (p2 + p3);
          Wd[msub][nblk2 * 2 + 0] = pkbf(p0, p1);
          Wd[msub][nblk2 * 2 + 1] = pkbf(p2, p3);
        }
      }
      // ---- in-register quad exchange: Wd -> pB (PV B-frag: lane needs
      // n_local = quad*8 + j for its m = msub*16 + l15) ----
      short8 pB[2];
#pragma unroll
      for (int msub = 0; msub < 2; ++msub) {
        u32 A0p, B0p, A1p, B1p;
        lane32_swap(Wd[msub][0], Wd[msub][2], A0p, B0p, hi32);
        lane32_swap(Wd[msub][1], Wd[msub][3], A1p, B1p, hi32);
        u32 G0 = lane16_xor(qodd ? A0p : B0p, qodd);
        u32 G1 = lane16_xor(qodd ? A1p : B1p, qodd);
        union { u32 u[4]; short8 s; } cvt;
        cvt.u[0] = qodd ? G0 : A0p;
        cvt.u[1] = qodd ? G1 : A1p;
        cvt.u[2] = qodd ? B0p : G0;
        cvt.u[3] = qodd ? B1p : G1;
        pB[msub] = cvt.s;
      }
      // ---- PV for this 32-n half: O^T += V^T · P^T (K=32) ----
#pragma unroll
      for (int dd = 0; dd < 4; ++dd) {
        int row = dd * 16 + l15;
        short8 vb = *(short8*)&vt[row * 64 + (((half * 4 + quad) ^ (row & 7)) << 3)];
#pragma unroll
        for (int msub = 0; msub < 2; ++msub)
          oacc[msub][dd] = __builtin_amdgcn_mfma_f32_16x16x32_bf16(vb, pB[msub], oacc[msub][dd], 0, 0, 0);
      }
    }
  }

  // ---- row-sum reduction (column m is held by 4 quad-lanes) ----
  float rinv[2];
#pragma unroll
  for (int msub = 0; msub < 2; ++msub) {
    float l = lsum[msub];
    l += __shfl_xor(l, 16);
    l += __shfl_xor(l, 32);
    rinv[msub] = 1.0f / l;
  }

  // ---- epilogue: wave-private LDS transpose (64dd x 34f = 8.5 KB/wave,
  // 68 KB total fits in the dead staging buffers), full-128B-line stores ----
  __syncthreads();   // all waves done with buffers before smem reuse
  float* ot = (float*)smem_u16 + w * 2176;   // 64dd x 34 floats
  int l8 = lane & 7, lr = lane >> 3;
#pragma unroll
  for (int msub = 0; msub < 2; ++msub)
#pragma unroll
    for (int dd = 0; dd < 4; ++dd)
#pragma unroll
      for (int r = 0; r < 4; ++r)
        ot[(dd * 16 + quad * 4 + r) * 34 + msub * 16 + l15] = oacc[msub][dd][r] * rinv[msub];
  // intra-wave LDS ops are in-order; no barrier needed
#pragma unroll
  for (int pass = 0; pass < 8; ++pass) {
    int dd = pass * 8 + lr;
    float4 o4 = *(float4*)&ot[dd * 34 + l8 * 4];
    size_t off = (((size_t)b * CCH + h * DH + dd) << 10) + mtile * 256 + w * 32 + l8 * 4;
    float4 xv = *(const float4*)&x[off];
    o4.x += xv.x; o4.y += xv.y; o4.z += xv.z; o4.w += xv.w;
    *(float4*)&out[off] = o4;
  }
}

extern "C" void kernel_launch(void* const* d_in, const int* in_sizes, int n_in,
                              void* d_out, int out_size, void* d_ws, size_t ws_size,
                              hipStream_t stream) {
  const float* x     = (const float*)d_in[0];
  const float* Wq    = (const float*)d_in[1];
  const float* bq    = (const float*)d_in[2];
  const float* Wk    = (const float*)d_in[3];
  const float* bk    = (const float*)d_in[4];
  const float* Wv    = (const float*)d_in[5];
  const float* bv    = (const float*)d_in[6];
  const float* rel_h = (const float*)d_in[7];
  const float* rel_w = (const float*)d_in[8];
  // d_in[9] (reg_qk) and d_in[10] (reg_v) provably do not affect the output.
  float* out = (float*)d_out;

  char* ws = (char*)d_ws;
  u16* qw   = (u16*)(ws);                          // 16 MB  [b,h,n,dd]
  u16* kw   = (u16*)(ws + ((size_t)16 << 20));     // 16 MB  [b,h,n,dd]
  u16* vtw  = (u16*)(ws + ((size_t)32 << 20));     // 16 MB  [bh][nt16][dd64][nn64]
  u16* pos  = (u16*)(ws + ((size_t)48 << 20));     // 1 MB   [h,n,dd]
  u16* wbf  = (u16*)(ws + ((size_t)49 << 20));     // 1.5 MB [which][o][c] bf16
  u16* xt   = (u16*)d_out;                         // xT bf16 parked in d_out (overwritten later)

  hipLaunchKernelGGL(prep_all, dim3(4864), dim3(256), 0, stream,
                     x, Wq, Wk, Wv, rel_h, rel_w, wbf, pos, xt);
  hipLaunchKernelGGL(qkv_fused, dim3(1024), dim3(256), 0, stream,
                     wbf, xt, bq, bk, bv, qw, kw, vtw);
  hipLaunchKernelGGL(attn_mfma, dim3(128, 4), dim3(512), 0, stream,
                     qw, kw, vtw, pos, x, out);
}

// Round 8
// 199.272 us; speedup vs baseline: 1.0880x; 1.0530x over previous
//
#include <hip/hip_runtime.h>

// Problem constants
#define BB   16
#define HEADS 8
#define DH   64
#define NSP  1024   // W*H = 32*32
#define CCH  512

typedef unsigned int   u32;
typedef unsigned short u16;
typedef __attribute__((ext_vector_type(8))) short  short8;   // 8 bf16 = 4 VGPR (MFMA A/B frag)
typedef __attribute__((ext_vector_type(4))) float  floatx4;  // MFMA C/D frag
typedef __attribute__((ext_vector_type(2))) unsigned uint2v;

#if defined(__has_builtin)
#if __has_builtin(__builtin_amdgcn_exp2f)
#define EXP2F(x) __builtin_amdgcn_exp2f(x)
#else
#define EXP2F(x) exp2f(x)
#endif
#if __has_builtin(__builtin_amdgcn_permlane32_swap)
#define HAVE_PL32 1
#endif
#if __has_builtin(__builtin_amdgcn_permlane16_swap)
#define HAVE_PL16 1
#endif
#else
#define EXP2F(x) exp2f(x)
#endif

__device__ __forceinline__ u16 f2b(float f) {
  u32 x = __float_as_uint(f);
  x = x + 0x7fffu + ((x >> 16) & 1u);   // RNE
  return (u16)(x >> 16);
}

// pack two fp32 -> two bf16 (round-half-up ~= RNE) in one v_perm_b32
__device__ __forceinline__ u32 pkbf(float lo, float hi) {
  return __builtin_amdgcn_perm(__float_as_uint(hi) + 0x8000u,
                               __float_as_uint(lo) + 0x8000u, 0x07060302u);
}

__device__ __forceinline__ void gload_lds16(const u16* g, u16* l) {
  __builtin_amdgcn_global_load_lds((const __attribute__((address_space(1))) u32*)g,
                                   (__attribute__((address_space(3))) u32*)l, 16, 0, 0);
}

// ---- cross-lane helpers for the in-register P quad-exchange ----
// lane32_swap(a,b): ap = {a.lo32lanes, b.lo32lanes}, bp = {a.hi, b.hi}
__device__ __forceinline__ void lane32_swap(u32 a, u32 b, u32& ap, u32& bp, bool hi32) {
#ifdef HAVE_PL32
  uint2v r = __builtin_amdgcn_permlane32_swap(a, b, false, false);
  ap = r.x; bp = r.y;
  (void)hi32;
#else
  u32 sb = (u32)__shfl_xor((int)b, 32);
  u32 sa = (u32)__shfl_xor((int)a, 32);
  ap = hi32 ? sb : a;
  bp = hi32 ? b : sa;
#endif
}

// returns x from lane^16 (quad-pair exchange 0<->1, 2<->3)
__device__ __forceinline__ u32 lane16_xor(u32 x, bool qodd) {
#ifdef HAVE_PL16
  uint2v r = __builtin_amdgcn_permlane16_swap(x, x, false, false);
  // r.x = {q0,q0,q2,q2}, r.y = {q1,q1,q3,q3} -> xor16 = qodd ? r.x : r.y
  return qodd ? r.x : r.y;
#else
  return (u32)__shfl_xor((int)x, 16);
#endif
}

// ============================================================================
// FRAGMENT-BLOCK LAYOUTS (R8): every attn main-loop operand is stored so that
// one wave's 64 lanes read 1024 contiguous bytes (global_load_dwordx4/lane):
//   kw/qw : [bh][nt16][nblk4][ks2][lane64][8 u16], lane = q*16 + r holds
//           row n = nt*64+nblk*16+r, dd chunk [ks*32+q*8, +8)
//   pos   : same form per h (rows m, chunks dd)
//   vtw   : [bh][nt16][ddblk4][nh2][lane64][8], lane = q*16+r holds
//           row dd = ddblk*16+r, n chunk [nh*32+q*8, +8)
// These deliver bit-identical register contents to the R3 LDS path
// (write-swizzle o read-swizzle = identity, chunk = quad).
// ============================================================================

// ---- fused prep: Wq/Wk/Wv cast (768 blk) | pos build (2048 blk) | x transpose (2048 blk)
__global__ __launch_bounds__(256) void prep_all(const float* __restrict__ x,
                                                const float* __restrict__ Wq,
                                                const float* __restrict__ Wk,
                                                const float* __restrict__ Wv,
                                                const float* __restrict__ rel_h,
                                                const float* __restrict__ rel_w,
                                                u16* __restrict__ wbf,
                                                u16* __restrict__ pos,
                                                u16* __restrict__ xt) {
  __shared__ float ld[64][68];
  int bid = blockIdx.x;
  int t = threadIdx.x;
  if (bid < 768) {
    // ---- W cast (o,c) fp32 -> bf16 ----
    int idx = bid * 256 + t;
    int which = idx >> 16;
    int r4 = (idx & 65535) * 4;
    const float* src = which == 0 ? Wq : which == 1 ? Wk : Wv;
    float4 v = *(const float4*)&src[r4];
    ushort4 s;
    s.x = f2b(v.x); s.y = f2b(v.y); s.z = f2b(v.z); s.w = f2b(v.w);
    *(ushort4*)&wbf[(which << 18) + r4] = s;
  } else if (bid < 2816) {
    // ---- pos fragment-block store ----
    int idx = (bid - 768) * 256 + t;
    int dd = idx & 63;
    int n  = (idx >> 6) & 1023;
    int hd = idx >> 16;
    int ww = n >> 5, hh = n & 31;
    float v = rel_h[(hd * 64 + dd) * 32 + hh] + rel_w[(hd * 64 + dd) * 32 + ww];
    int ntp = n >> 6, nbp = (n >> 4) & 3, rp = n & 15;
    int ksp = dd >> 5, qp = (dd >> 3) & 3, ep = dd & 7;
    size_t off = ((((size_t)(hd * 16 + ntp) * 4 + nbp) * 2 + ksp) * 64 + qp * 16 + rp) * 8 + ep;
    pos[off] = f2b(v);
  } else {
    // ---- x [b][c][n] fp32 -> xt [b][n][c] bf16, 64x64 LDS tile ----
    int bid2 = bid - 2816;
    int ntile = bid2 & 15, ctile = (bid2 >> 4) & 7, b = bid2 >> 7;
    const float* xb = x + (((size_t)b * CCH + ctile * 64) << 10) + ntile * 64;
#pragma unroll
    for (int p = 0; p < 4; ++p) {
      int c = p * 16 + (t >> 4), n4 = (t & 15) * 4;
      float4 v = *(const float4*)&xb[((size_t)c << 10) + n4];
      ld[c][n4 + 0] = v.x; ld[c][n4 + 1] = v.y; ld[c][n4 + 2] = v.z; ld[c][n4 + 3] = v.w;
    }
    __syncthreads();
    u16* xo = xt + (((size_t)b << 10) + ntile * 64) * CCH + ctile * 64;
#pragma unroll
    for (int p = 0; p < 2; ++p) {
      int id = p * 256 + t;
      int n = id >> 3, c8 = (id & 7) * 8;
      ushort4 s0, s1;
      s0.x = f2b(ld[c8 + 0][n]); s0.y = f2b(ld[c8 + 1][n]);
      s0.z = f2b(ld[c8 + 2][n]); s0.w = f2b(ld[c8 + 3][n]);
      s1.x = f2b(ld[c8 + 4][n]); s1.y = f2b(ld[c8 + 5][n]);
      s1.z = f2b(ld[c8 + 6][n]); s1.w = f2b(ld[c8 + 7][n]);
      *(ushort4*)&xo[(size_t)n * CCH + c8] = s0;
      *(ushort4*)&xo[(size_t)n * CCH + c8 + 4] = s1;
    }
  }
}

// ---- FUSED QKV projection with T4 schedule + XCD-aware block remap.
// Compute identical to R4; epilogue stores re-indexed to fragment-block layouts.
__global__ __launch_bounds__(256, 2) void qkv_fused(const u16* __restrict__ wbf,
                                                    const u16* __restrict__ xt,
                                                    const float* __restrict__ bq,
                                                    const float* __restrict__ bk,
                                                    const float* __restrict__ bv,
                                                    u16* __restrict__ qw,
                                                    u16* __restrict__ kw,
                                                    u16* __restrict__ vtw) {
  int hid = blockIdx.x;             // 0..1023
  int xcd  = hid & 7;
  int slot = hid >> 3;              // 0..127
  int otile = slot & 7;
  int pair  = xcd * 16 + (slot >> 3);   // 0..127
  int ntile = pair & 7;
  int b     = pair >> 3;
  int o0 = otile * 64, n0 = ntile * 128;

  __shared__ __align__(16) u16 smem[2 * 20480];   // 80 KB: buf { Wq64 | Wk64 | Wv64 | X128 } x64c

  int t = threadIdx.x;
  int w = t >> 6, lane = t & 63;
  int l15 = lane & 15, quad = lane >> 4;
  int srow = lane >> 3, sc = lane & 7;
  int scc = (sc ^ srow) << 3;

  floatx4 aq[8], ak[8], av[8];
#pragma unroll
  for (int i = 0; i < 8; ++i) {
    aq[i] = (floatx4){0.f, 0.f, 0.f, 0.f};
    ak[i] = (floatx4){0.f, 0.f, 0.f, 0.f};
    av[i] = (floatx4){0.f, 0.f, 0.f, 0.f};
  }

  // staging: 320 rows of 64c: [0,64)Wq [64,128)Wk [128,192)Wv [192,320)X; 10 glds/wave
  auto stage = [&](int k0, int buf) {
    u16* base = smem + buf * 20480;
#pragma unroll
    for (int p = 0; p < 10; ++p) {
      int g0 = w * 80 + p * 8;     // uniform 8-row group base (tile bounds are x8)
      if (g0 < 192) {
        int which = g0 >> 6;
        int r0 = g0 & 63;
        gload_lds16(wbf + ((size_t)which << 18) + (size_t)(o0 + r0 + srow) * CCH + k0 + scc,
                    base + which * 4096 + r0 * 64);
      } else {
        int r0 = g0 - 192;
        gload_lds16(xt + (size_t)(b * 1024 + n0 + r0 + srow) * CCH + k0 + scc,
                    base + 12288 + r0 * 64);
      }
    }
  };

  int rs = l15 & 7;
  int c0 = (quad ^ rs) << 3;
  int c1 = ((4 + quad) ^ rs) << 3;
  int wrow = (w * 16 + l15) * 64;

  stage(0, 0);    // prologue DMA: 2-deep prefetch
  stage(64, 1);

  for (int ki = 0; ki < 8; ++ki) {
    // wait for THIS step's 10 DMAs only; step ki+1's 10 stay in flight
    if (ki < 7) asm volatile("s_waitcnt vmcnt(10)" ::: "memory");
    else        asm volatile("s_waitcnt vmcnt(0)" ::: "memory");
    __builtin_amdgcn_s_barrier();
    __builtin_amdgcn_sched_barrier(0);

    u16* base = smem + (ki & 1) * 20480;
    u16* Xb = base + 12288;
#pragma unroll
    for (int ks = 0; ks < 2; ++ks) {
      int cc = ks ? c1 : c0;
      short8 fq = *(short8*)&base[wrow + cc];
      short8 fk = *(short8*)&base[4096 + wrow + cc];
      short8 fv = *(short8*)&base[8192 + wrow + cc];
#pragma unroll
      for (int ns = 0; ns < 8; ++ns) {
        short8 fx = *(short8*)&Xb[(ns * 16 + l15) * 64 + cc];
        aq[ns] = __builtin_amdgcn_mfma_f32_16x16x32_bf16(fq, fx, aq[ns], 0, 0, 0);
        ak[ns] = __builtin_amdgcn_mfma_f32_16x16x32_bf16(fk, fx, ak[ns], 0, 0, 0);
        av[ns] = __builtin_amdgcn_mfma_f32_16x16x32_bf16(fx, fv, av[ns], 0, 0, 0);
      }
    }

    // post-compute join: buffer ki&1 dead for all waves before re-staging
    if (ki < 6) {
      __builtin_amdgcn_sched_barrier(0);
      __builtin_amdgcn_s_barrier();
      stage((ki + 2) * 64, ki & 1);
    }
  }

  // ---- epilogue: all three tiles through padded LDS -> fragment-block stores ----
  __syncthreads();                 // staging buffers dead; reuse as transpose scratch
  u16* epQ = smem;                 // [128 n][72]  (144B rows, 16B-aligned)
  u16* epK = smem + 9216;
  u16* epV = smem + 18432;         // [64 o][136]  (272B rows)
  {
    int ob = o0 + w * 16 + quad * 4;
    float q0 = bq[ob], q1 = bq[ob + 1], q2 = bq[ob + 2], q3 = bq[ob + 3];
    float k0b = bk[ob], k1b = bk[ob + 1], k2b = bk[ob + 2], k3b = bk[ob + 3];
    float vb = bv[o0 + w * 16 + l15];
#pragma unroll
    for (int ns = 0; ns < 8; ++ns) {
      int n = ns * 16 + l15;
      uint2 pk;
      pk.x = pkbf(aq[ns][0] + q0, aq[ns][1] + q1);
      pk.y = pkbf(aq[ns][2] + q2, aq[ns][3] + q3);
      *(uint2*)&epQ[n * 72 + w * 16 + quad * 4] = pk;
      pk.x = pkbf(ak[ns][0] + k0b, ak[ns][1] + k1b);
      pk.y = pkbf(ak[ns][2] + k2b, ak[ns][3] + k3b);
      *(uint2*)&epK[n * 72 + w * 16 + quad * 4] = pk;
      pk.x = pkbf(av[ns][0] + vb, av[ns][1] + vb);
      pk.y = pkbf(av[ns][2] + vb, av[ns][3] + vb);
      *(uint2*)&epV[(w * 16 + l15) * 136 + ns * 16 + quad * 4] = pk;
    }
  }
  __syncthreads();
  int h = otile;
  size_t bhI = (size_t)(b * HEADS + h);
  {
    // Q/K -> [bh][nt][nblk][ks][lane][8]: thread (row, half=ks) writes 4 chunks q=i
    int row = t >> 1, half = t & 1;
    int nt_ = (n0 + row) >> 6;
    int nblk_ = (row >> 4) & 3;
    int r_ = row & 15;
    size_t qkbase = (((bhI * 16 + nt_) * 4 + nblk_) * 2 + half) * 512;
#pragma unroll
    for (int i = 0; i < 4; ++i)
      *(uint4*)&qw[qkbase + (i * 16 + r_) * 8] = *(uint4*)&epQ[row * 72 + half * 32 + i * 8];
#pragma unroll
    for (int i = 0; i < 4; ++i)
      *(uint4*)&kw[qkbase + (i * 16 + r_) * 8] = *(uint4*)&epK[row * 72 + half * 32 + i * 8];
  }
  {
    // V -> [bh][nt][ddblk][nh][lane][8]: thread (row=dd, q4) writes 4 n-chunks
    int row = t >> 2, q4 = t & 3;
    int ddblk = row >> 4, r_ = row & 15;
#pragma unroll
    for (int i = 0; i < 4; ++i) {
      int nl = q4 * 32 + i * 8;
      int n = n0 + nl;
      int ntv = n >> 6, np = n & 63;
      int nh = np >> 5, q = (np >> 3) & 3;
      size_t vbase = (((bhI * 16 + ntv) * 4 + ddblk) * 2 + nh) * 512;
      *(uint4*)&vtw[vbase + (q * 16 + r_) * 8] = *(uint4*)&epV[row * 136 + nl];
    }
  }
}

// ---- MFMA flash attention (R8): NO LDS staging, NO barriers in the main loop.
// K/Q/V/pos are pre-stored in fragment-block layout; every operand is a fully
// coalesced 1-KB global_load_dwordx4 served by the XCD-local L2 (KQV per bh =
// 384 KB; the 4 mtile blocks of a bh are 128 apart in id = same XCD). This
// removes the structure that plateaued at 71-73 us across 5 schedule variants
// (R2-R5) and applies the m169 precedent (+26% from de-staging L2-fit data).
// Math and FP order identical to R3 -> bit-identical output.
__global__ __launch_bounds__(256, 2) void attn_mfma(const u16* __restrict__ qw,
                                                    const u16* __restrict__ kw,
                                                    const u16* __restrict__ vtw,
                                                    const u16* __restrict__ pos,
                                                    const float* __restrict__ x,
                                                    float* __restrict__ out) {
  int bh = blockIdx.x, mtile = blockIdx.y;
  int b = bh >> 3, h = bh & 7;
  __shared__ __align__(16) float smem_f[9216];   // 36 KB epilogue scratch (per-wave)

  int t = threadIdx.x;
  int w = t >> 6, lane = t & 63;
  int l15 = lane & 15, quad = lane >> 4;
  bool qodd = (quad & 1) != 0;
  bool hi32 = lane >= 32;
  size_t bhs = (size_t)bh;
  int lane8 = lane * 8;

  // loop-invariant fragments: q_m, pos_m (MFMA B-operands), 64 rows per wave
  short8 qa[4][2], pa[4][2];
  {
    const u16* qmb = qw + bhs * 65536 + (size_t)(mtile * 4 + w) * 4096;
    const u16* pmb = pos + (size_t)h * 65536 + (size_t)(mtile * 4 + w) * 4096;
#pragma unroll
    for (int msub = 0; msub < 4; ++msub)
#pragma unroll
      for (int ks = 0; ks < 2; ++ks) {
        int off = (msub * 2 + ks) * 512 + lane8;
        qa[msub][ks] = *(const short8*)(qmb + off);
        pa[msub][ks] = *(const short8*)(pmb + off);
      }
  }

  floatx4 oacc[4][4];   // [msub][ddsub]: dd = ddsub*16+quad*4+r, m = msub*16+l15
  float lsum[4] = {0.f, 0.f, 0.f, 0.f};
#pragma unroll
  for (int i = 0; i < 4; ++i)
#pragma unroll
    for (int j = 0; j < 4; ++j) oacc[i][j] = (floatx4){0.f, 0.f, 0.f, 0.f};

  const u16* kg = kw + bhs * 65536;
  const u16* qg = qw + bhs * 65536;
  const u16* vg = vtw + bhs * 65536;

  for (int nt = 0; nt < 16; ++nt) {
    const u16* kgt = kg + nt * 4096;
    const u16* qgt = qg + nt * 4096;
    const u16* vgt = vg + nt * 4096;

    // ---- hoisted coalesced operand loads (compiler inserts counted waits) ----
    short8 kb[4][2], qb[4][2], vb[4][2];
#pragma unroll
    for (int nblk = 0; nblk < 4; ++nblk)
#pragma unroll
      for (int ks = 0; ks < 2; ++ks) {
        int off = (nblk * 2 + ks) * 512 + lane8;
        kb[nblk][ks] = *(const short8*)(kgt + off);
        qb[nblk][ks] = *(const short8*)(qgt + off);
      }
#pragma unroll
    for (int dd = 0; dd < 4; ++dd)
#pragma unroll
      for (int hf = 0; hf < 2; ++hf)
        vb[dd][hf] = *(const short8*)(vgt + (dd * 2 + hf) * 512 + lane8);

#pragma unroll
    for (int half = 0; half < 2; ++half) {
      // ---- S^T + softmax numerator for 32 n (2 nblk); P stays in registers ----
      u32 Wd[4][4];   // [msub][word]: word nblk2*2+rp packs n_local = nblk2*16+quad*4+2rp,+1
#pragma unroll
      for (int nblk2 = 0; nblk2 < 2; ++nblk2) {
        int nblk = half * 2 + nblk2;
        floatx4 sc4[4];
#pragma unroll
        for (int msub = 0; msub < 4; ++msub) {
          floatx4 c = (floatx4){0.f, 0.f, 0.f, 0.f};
          c = __builtin_amdgcn_mfma_f32_16x16x32_bf16(kb[nblk][0], qa[msub][0], c, 0, 0, 0);
          c = __builtin_amdgcn_mfma_f32_16x16x32_bf16(kb[nblk][1], qa[msub][1], c, 0, 0, 0);
          c = __builtin_amdgcn_mfma_f32_16x16x32_bf16(qb[nblk][0], pa[msub][0], c, 0, 0, 0);
          c = __builtin_amdgcn_mfma_f32_16x16x32_bf16(qb[nblk][1], pa[msub][1], c, 0, 0, 0);
          sc4[msub] = c;
        }
#pragma unroll
        for (int msub = 0; msub < 4; ++msub) {
          // p = exp(s - 8) = exp2(s*log2e - 8*log2e)
          float p0 = EXP2F(fmaf(sc4[msub][0], 1.44269504f, -11.5415603f));
          float p1 = EXP2F(fmaf(sc4[msub][1], 1.44269504f, -11.5415603f));
          float p2 = EXP2F(fmaf(sc4[msub][2], 1.44269504f, -11.5415603f));
          float p3 = EXP2F(fmaf(sc4[msub][3], 1.44269504f, -11.5415603f));
          lsum[msub] += (p0 + p1) + (p2 + p3);
          Wd[msub][nblk2 * 2 + 0] = pkbf(p0, p1);
          Wd[msub][nblk2 * 2 + 1] = pkbf(p2, p3);
        }
      }
      // ---- in-register quad exchange: Wd -> pB (PV B-frag: lane needs
      // n_local = quad*8 + j for its m = msub*16 + l15) ----
      short8 pB[4];
#pragma unroll
      for (int msub = 0; msub < 4; ++msub) {
        u32 A0p, B0p, A1p, B1p;
        lane32_swap(Wd[msub][0], Wd[msub][2], A0p, B0p, hi32);
        lane32_swap(Wd[msub][1], Wd[msub][3], A1p, B1p, hi32);
        u32 G0 = lane16_xor(qodd ? A0p : B0p, qodd);
        u32 G1 = lane16_xor(qodd ? A1p : B1p, qodd);
        union { u32 u[4]; short8 s; } cvt;
        cvt.u[0] = qodd ? G0 : A0p;
        cvt.u[1] = qodd ? G1 : A1p;
        cvt.u[2] = qodd ? B0p : G0;
        cvt.u[3] = qodd ? B1p : G1;
        pB[msub] = cvt.s;
      }
      // ---- PV for this 32-n half: O^T += V^T · P^T (K=32) ----
#pragma unroll
      for (int dd = 0; dd < 4; ++dd) {
#pragma unroll
        for (int msub = 0; msub < 4; ++msub)
          oacc[msub][dd] = __builtin_amdgcn_mfma_f32_16x16x32_bf16(vb[dd][half], pB[msub], oacc[msub][dd], 0, 0, 0);
      }
    }
  }

  // ---- row-sum reduction (column m is held by 4 quad-lanes) ----
  float rinv[4];
#pragma unroll
  for (int msub = 0; msub < 4; ++msub) {
    float l = lsum[msub];
    l += __shfl_xor(l, 16);
    l += __shfl_xor(l, 32);
    rinv[msub] = 1.0f / l;
  }

  // ---- epilogue: wave-private LDS transpose (no barrier needed), float4 stores ----
  float* ot = smem_f + w * 2304;   // 64dd x 36
  int l8 = lane & 7, lr = lane >> 3;
#pragma unroll
  for (int mh = 0; mh < 2; ++mh) {
#pragma unroll
    for (int ms2 = 0; ms2 < 2; ++ms2) {
      int msub = mh * 2 + ms2;
#pragma unroll
      for (int dd = 0; dd < 4; ++dd)
#pragma unroll
        for (int r = 0; r < 4; ++r)
          ot[(dd * 16 + quad * 4 + r) * 36 + ms2 * 16 + l15] = oacc[msub][dd][r] * rinv[msub];
    }
    // intra-wave LDS ops are in-order; no barrier needed
#pragma unroll
    for (int pass = 0; pass < 8; ++pass) {
      int dd = pass * 8 + lr;
      float4 o4 = *(float4*)&ot[dd * 36 + l8 * 4];
      size_t off = (((size_t)b * CCH + h * DH + dd) << 10) + mtile * 256 + w * 64 + mh * 32 + l8 * 4;
      float4 xv = *(const float4*)&x[off];
      o4.x += xv.x; o4.y += xv.y; o4.z += xv.z; o4.w += xv.w;
      *(float4*)&out[off] = o4;
    }
  }
}

extern "C" void kernel_launch(void* const* d_in, const int* in_sizes, int n_in,
                              void* d_out, int out_size, void* d_ws, size_t ws_size,
                              hipStream_t stream) {
  const float* x     = (const float*)d_in[0];
  const float* Wq    = (const float*)d_in[1];
  const float* bq    = (const float*)d_in[2];
  const float* Wk    = (const float*)d_in[3];
  const float* bk    = (const float*)d_in[4];
  const float* Wv    = (const float*)d_in[5];
  const float* bv    = (const float*)d_in[6];
  const float* rel_h = (const float*)d_in[7];
  const float* rel_w = (const float*)d_in[8];
  // d_in[9] (reg_qk) and d_in[10] (reg_v) provably do not affect the output.
  float* out = (float*)d_out;

  char* ws = (char*)d_ws;
  u16* qw   = (u16*)(ws);                          // 16 MB  frag-block layout
  u16* kw   = (u16*)(ws + ((size_t)16 << 20));     // 16 MB  frag-block layout
  u16* vtw  = (u16*)(ws + ((size_t)32 << 20));     // 16 MB  frag-block layout
  u16* pos  = (u16*)(ws + ((size_t)48 << 20));     // 1 MB   frag-block layout
  u16* wbf  = (u16*)(ws + ((size_t)49 << 20));     // 1.5 MB [which][o][c] bf16
  u16* xt   = (u16*)d_out;                         // xT bf16 parked in d_out (overwritten later)

  hipLaunchKernelGGL(prep_all, dim3(4864), dim3(256), 0, stream,
                     x, Wq, Wk, Wv, rel_h, rel_w, wbf, pos, xt);
  hipLaunchKernelGGL(qkv_fused, dim3(1024), dim3(256), 0, stream,
                     wbf, xt, bq, bk, bv, qw, kw, vtw);
  hipLaunchKernelGGL(attn_mfma, dim3(128, 4), dim3(256), 0, stream,
                     qw, kw, vtw, pos, x, out);
}